// Round 7
// baseline (375.178 us; speedup 1.0000x reference)
//
#include <hip/hip_runtime.h>
#include <hip/hip_bf16.h>
#include <cstdint>
#include <cstddef>

// Problem constants
#define NTOK 32768   // P*N*K token-copies
#define FD   256     // input feature dim
#define HD   1024    // hidden dim
#define OD   256     // output dim
#define NEXP 8

// GEMM tiling
#define BM 128
#define BN 128
#define BK 64
#define RT8 34       // ceil(max 128-row tiles / 8)

typedef __bf16 bf16;
typedef __bf16 bf16x8 __attribute__((ext_vector_type(8)));
typedef __bf16 bf16x4 __attribute__((ext_vector_type(4)));
typedef float  f32x4  __attribute__((ext_vector_type(4)));

// async global->LDS, 16 B per lane. LDS dst MUST be wave-uniform base + lane*16.
__device__ __forceinline__ void cp16(const void* g, void* l) {
    __builtin_amdgcn_global_load_lds(
        (const __attribute__((address_space(1))) void*)g,
        (__attribute__((address_space(3))) void*)l, 16, 0, 0);
}

// ---- workspace layout (bytes) ----
static const size_t O_CNT  = 0;          // int[8]
static const size_t O_CUR  = 64;         // int[8]
static const size_t O_OFF  = 128;        // int[9]
static const size_t O_NT   = 192;        // int[1]
static const size_t O_DONE = 240;        // int[1]  (hist last-block ticket)
static const size_t O_TE   = 1024;       // int[<=264 used]
static const size_t O_TR   = 3072;       // int[<=264 used]
static const size_t O_PERM = 5120;       // int[NTOK]
static const size_t O_XP   = 136192;     // bf16 [NTOK][FD]    (16 MB)
static const size_t O_WG   = 16913408;   // bf16 [E][HD][FD]   (4 MB)
static const size_t O_WU   = 21107712;   // bf16 [E][HD][FD]   (4 MB)
static const size_t O_W1   = 25302016;   // bf16 [E][HD][HD]   (16 MB)
static const size_t O_W2   = 42079232;   // bf16 [E][OD][HD]   (4 MB)
static const size_t O_H    = 46273536;   // bf16 [NTOK][HD]    (64 MB) Hbuf
static const size_t O_H2   = 113382400;  // bf16 [NTOK][HD]    (64 MB) H2

// ---------------- routing ----------------
// hist + plan fused: last block (device-scope ticket) runs the serial plan.
__global__ void k_histplan(const int* __restrict__ sel, int* __restrict__ cnt,
                           int* __restrict__ done, int* __restrict__ off,
                           int* __restrict__ tileE, int* __restrict__ tileR,
                           int* __restrict__ nt) {
    __shared__ int lcnt[NEXP];
    int tid = threadIdx.x;
    if (tid < NEXP) lcnt[tid] = 0;
    __syncthreads();
    int t = blockIdx.x * 256 + tid;   // NTOK % 256 == 0
    atomicAdd(&lcnt[sel[t]], 1);
    __syncthreads();
    if (tid < NEXP) atomicAdd(&cnt[tid], lcnt[tid]);
    __syncthreads();                  // block's cnt atomics issued before ticket
    if (tid == 0) {
        __threadfence();              // order cnt RMWs before ticket RMW
        int ret = atomicAdd(done, 1);
        if (ret == (int)gridDim.x - 1) {
            int c[NEXP];
            int o = 0;
            for (int e = 0; e < NEXP; e++) {
                c[e] = atomicAdd(&cnt[e], 0);
                off[e] = o; o += c[e];
            }
            off[NEXP] = o;
            int n = 0;
            for (int e = 0; e < NEXP; e++) {
                int nte = (c[e] + BM - 1) / BM;
                for (int r = 0; r < nte; r++) { tileE[n] = e; tileR[n] = r; n++; }
            }
            *nt = n;
        }
    }
}

// scatter + gather fused: block computes perm for its 128 tokens, then its
// 4 waves copy the rows x[tok] (fp32) -> Xp[pos] (bf16) directly.
__global__ void k_scatgath(const int* __restrict__ sel, const int* __restrict__ off,
                           int* __restrict__ cur, int* __restrict__ perm,
                           const float* __restrict__ x, bf16* __restrict__ Xp) {
    __shared__ int lcnt[NEXP];
    __shared__ int lbase[NEXP];
    __shared__ int lpos[128];
    __shared__ int ltok[128];
    int tid = threadIdx.x;
    if (tid < NEXP) lcnt[tid] = 0;
    __syncthreads();
    int e = 0, rank = 0, t = 0;
    if (tid < 128) {
        t = blockIdx.x * 128 + tid;   // NTOK % 128 == 0, grid = NTOK/128
        e = sel[t];
        rank = atomicAdd(&lcnt[e], 1);
    }
    __syncthreads();
    if (tid < NEXP)
        lbase[tid] = atomicAdd(&cur[tid], lcnt[tid]);
    __syncthreads();
    if (tid < 128) {
        int pos = off[e] + lbase[e] + rank;
        perm[pos] = t;
        lpos[tid] = pos;
        ltok[tid] = t;
    }
    __syncthreads();
    int lane = tid & 63, wv = tid >> 6;
    for (int r = wv; r < 128; r += 4) {
        int tok = ltok[r], pos = lpos[r];
        float4 v = ((const float4*)x)[(size_t)tok * 64 + lane];
        bf16x4 o;
        o.x = (bf16)v.x; o.y = (bf16)v.y; o.z = (bf16)v.z; o.w = (bf16)v.w;
        *(bf16x4*)&Xp[(size_t)pos * FD + lane * 4] = o;
    }
}

// All 4 weight transposes in ONE launch. W [E][K][N] fp32 -> Wt [E][N][K] bf16.
#define TPE 448
__global__ void k_transpose_all(const float* __restrict__ Wg, bf16* __restrict__ Wgt,
                                const float* __restrict__ Wu, bf16* __restrict__ Wut,
                                const float* __restrict__ W1, bf16* __restrict__ W1t,
                                const float* __restrict__ W2, bf16* __restrict__ W2t) {
    __shared__ float tile[64][65];
    int b  = blockIdx.x;
    int e  = b / TPE;
    int tt = b % TPE;
    const float* Ws; bf16* Wd; int K, N;
    if (tt < 64)       { Ws = Wg; Wd = Wgt; K = FD; N = HD; }
    else if (tt < 128) { Ws = Wu; Wd = Wut; K = FD; N = HD; tt -= 64; }
    else if (tt < 384) { Ws = W1; Wd = W1t; K = HD; N = HD; tt -= 128; }
    else               { Ws = W2; Wd = W2t; K = HD; N = OD; tt -= 384; }
    int nk = K / 64;
    int k0 = (tt % nk) * 64, n0 = (tt / nk) * 64;
    Ws += (size_t)e * K * N;
    Wd += (size_t)e * K * N;
    int t = threadIdx.x;
    for (int q = 0; q < 4; q++) {
        int lin = t + q * 256;
        int r = lin >> 4, c4 = (lin & 15) * 4;
        float4 v = *(const float4*)&Ws[(size_t)(k0 + r) * N + n0 + c4];
        tile[r][c4] = v.x; tile[r][c4+1] = v.y; tile[r][c4+2] = v.z; tile[r][c4+3] = v.w;
    }
    __syncthreads();
    for (int q = 0; q < 2; q++) {   // 64 n * 8 chunks = 512 items
        int lin = t + q * 256;
        int n = lin >> 3, k8 = (lin & 7) * 8;
        bf16x8 o;
        for (int i = 0; i < 8; i++) o[i] = (bf16)tile[k8 + i][n];
        *(bf16x8*)&Wd[(size_t)(n0 + n) * K + k0 + k8] = o;
    }
}

// ---------------- GEMM kernels ----------------
// MFMA 16x16x32 bf16 (HW-verified layouts). BK=64: 2 k-steps per barrier.
// LDS: unpadded [rows][64], XOR chunk swizzle over 8 chunks/row.
// XCD swizzle: 1D grid, xcd=L&7 -> all n-tiles of a row-tile on one XCD.

#define DECODE_TILE(NTY, BNE)                                                  \
    int L = blockIdx.x;                                                        \
    int xcd = L & 7; int tq = L >> 3;                                          \
    int ny  = tq % (NTY); int Rhi = tq / (NTY);                                \
    int R   = Rhi * 8 + xcd;                                                   \
    if (R >= *ntp) return;                                                     \
    int e    = tileE[R];                                                       \
    int row0 = tileR[R] * BM;                                                  \
    int base = off[e];                                                         \
    int valid = off[e + 1] - base - row0; if (valid > BM) valid = BM;          \
    int n0 = ny * (BNE);                                                       \
    int tid = threadIdx.x;                                                     \
    int lane = tid & 63, wv = tid >> 6;                                        \
    int wm = wv & 1, wn = wv >> 1;                                             \
    int lr = lane & 15, qd = lane >> 4;

#define GEMM_KLOOP(KDIM)                                                       \
    for (int k0 = 0; k0 < (KDIM); k0 += BK) {                                  \
        for (int s = 0; s < 4; s++) {                                          \
            int ci = tid + s * 256;                                            \
            int row = ci >> 3;                                                 \
            int jg  = (ci & 7) ^ (row & 7);                                    \
            int mc  = row < valid ? row : valid - 1;                           \
            cp16(Ab + (size_t)mc  * (KDIM) + k0 + jg * 8, &As[ci * 8]);        \
            cp16(Bb + (size_t)row * (KDIM) + k0 + jg * 8, &Bs[ci * 8]);        \
        }                                                                      \
        __syncthreads();                                                       \
        for (int ks = 0; ks < 2; ks++) {                                       \
            bf16x8 af[4], bfr[4];                                              \
            for (int i = 0; i < 4; i++) {                                      \
                int row = wm * 64 + i * 16 + lr;                               \
                int sl  = (ks * 4 + qd) ^ (row & 7);                           \
                af[i] = *(const bf16x8*)&As[row * BK + sl * 8];                \
            }                                                                  \
            for (int j = 0; j < 4; j++) {                                      \
                int row = wn * 64 + j * 16 + lr;                               \
                int sl  = (ks * 4 + qd) ^ (row & 7);                           \
                bfr[j] = *(const bf16x8*)&Bs[row * BK + sl * 8];               \
            }                                                                  \
            for (int i = 0; i < 4; i++)                                        \
                for (int j = 0; j < 4; j++)                                    \
                    acc[i][j] = __builtin_amdgcn_mfma_f32_16x16x32_bf16(       \
                        af[i], bfr[j], acc[i][j], 0, 0, 0);                    \
        }                                                                      \
        __syncthreads();                                                       \
    }

// Fused SwiGLU: Hbuf = silu(Xp@Wg+bg) * (Xp@Wu+bu). BM=128 x BN=64, K=FD=256.
__global__ __launch_bounds__(256, 4) void k_swiglu(
    const bf16* __restrict__ Xp, const bf16* __restrict__ Wgt, const bf16* __restrict__ Wut,
    const float* __restrict__ bg, const float* __restrict__ bu, bf16* __restrict__ Hbuf,
    const int* __restrict__ tileE, const int* __restrict__ tileR,
    const int* __restrict__ off, const int* __restrict__ ntp)
{
    __shared__ bf16 As [BM * BK];        // 16 KB
    __shared__ bf16 Bgs[64 * BK];        // 8 KB
    __shared__ bf16 Bus[64 * BK];        // 8 KB
    DECODE_TILE(16, 64)

    f32x4 accg[4][2] = {};
    f32x4 accu[4][2] = {};
    const bf16* Ab  = Xp  + (size_t)(base + row0) * FD;
    const bf16* Bgb = Wgt + ((size_t)e * HD + n0) * FD;
    const bf16* Bub = Wut + ((size_t)e * HD + n0) * FD;

    for (int k0 = 0; k0 < FD; k0 += BK) {
        for (int s = 0; s < 4; s++) {                  // A: 1024 chunks
            int ci = tid + s * 256;
            int row = ci >> 3;
            int jg  = (ci & 7) ^ (row & 7);
            int mc  = row < valid ? row : valid - 1;
            cp16(Ab + (size_t)mc * FD + k0 + jg * 8, &As[ci * 8]);
        }
        for (int s = 0; s < 2; s++) {                  // Bg,Bu: 512 chunks each
            int ci = tid + s * 256;
            int row = ci >> 3;
            int jg  = (ci & 7) ^ (row & 7);
            cp16(Bgb + (size_t)row * FD + k0 + jg * 8, &Bgs[ci * 8]);
            cp16(Bub + (size_t)row * FD + k0 + jg * 8, &Bus[ci * 8]);
        }
        __syncthreads();
        for (int ks = 0; ks < 2; ks++) {
            bf16x8 af[4], bgf[2], buf[2];
            for (int i = 0; i < 4; i++) {
                int row = wm * 64 + i * 16 + lr;
                int sl  = (ks * 4 + qd) ^ (row & 7);
                af[i] = *(const bf16x8*)&As[row * BK + sl * 8];
            }
            for (int j = 0; j < 2; j++) {
                int row = wn * 32 + j * 16 + lr;
                int sl  = (ks * 4 + qd) ^ (row & 7);
                bgf[j] = *(const bf16x8*)&Bgs[row * BK + sl * 8];
                buf[j] = *(const bf16x8*)&Bus[row * BK + sl * 8];
            }
            for (int i = 0; i < 4; i++)
                for (int j = 0; j < 2; j++) {
                    accg[i][j] = __builtin_amdgcn_mfma_f32_16x16x32_bf16(af[i], bgf[j], accg[i][j], 0, 0, 0);
                    accu[i][j] = __builtin_amdgcn_mfma_f32_16x16x32_bf16(af[i], buf[j], accu[i][j], 0, 0, 0);
                }
        }
        __syncthreads();
    }
    for (int i = 0; i < 4; i++) {
        int rb = wm * 64 + i * 16 + qd * 4;
        for (int r = 0; r < 4; r++) {
            int m = rb + r;
            if (m >= valid) continue;
            size_t orow = (size_t)(base + row0 + m) * HD;
            for (int j = 0; j < 2; j++) {
                int n = n0 + wn * 32 + j * 16 + lr;
                float g = accg[i][j][r] + bg[e * HD + n];
                float u = accu[i][j][r] + bu[e * HD + n];
                float h = g * u / (1.f + __expf(-g));   // silu(g)*u
                Hbuf[orow + n] = (bf16)h;
            }
        }
    }
}

// gemm2: H2 = relu(Hbuf@W1 + b1). K=HD. Split into 2 dispatches over N-halves
// (nyBase = 0 or 4, NTY=4 each): halves are fully independent (disjoint output
// cols). Diagnostic: drops per-dispatch dur to ~44us so the next-longest
// kernel surfaces in the top-5 table. Body identical to the proven structure.
__global__ __launch_bounds__(256, 4) void k_gemm2(
    const bf16* __restrict__ Ain, const bf16* __restrict__ Bt, const float* __restrict__ bias,
    bf16* __restrict__ Out, int nyBase,
    const int* __restrict__ tileE, const int* __restrict__ tileR,
    const int* __restrict__ off, const int* __restrict__ ntp)
{
    __shared__ bf16 As[BM * BK];   // 16 KB
    __shared__ bf16 Bs[BN * BK];   // 16 KB
    DECODE_TILE(4, BN)
    n0 += nyBase * BN;
    f32x4 acc[4][4] = {};
    const bf16* Ab = Ain + (size_t)(base + row0) * HD;
    const bf16* Bb = Bt  + ((size_t)e * HD + n0) * HD;
    GEMM_KLOOP(HD)
    for (int i = 0; i < 4; i++) {
        int rb = wm * 64 + i * 16 + qd * 4;
        for (int r = 0; r < 4; r++) {
            int m = rb + r;
            if (m >= valid) continue;
            size_t orow = (size_t)(base + row0 + m) * HD;
            for (int j = 0; j < 4; j++) {
                int n = n0 + wn * 64 + j * 16 + lr;
                float v = acc[i][j][r] + bias[e * HD + n];
                Out[orow + n] = (bf16)(v > 0.f ? v : 0.f);
            }
        }
    }
}

// gemm3: out[perm] = H2@W2 + b2 (fp32 scatter). K=HD, NTY=2.
__global__ __launch_bounds__(256, 4) void k_gemm3(
    const bf16* __restrict__ Ain, const bf16* __restrict__ Bt, const float* __restrict__ bias,
    float* __restrict__ out, const int* __restrict__ perm,
    const int* __restrict__ tileE, const int* __restrict__ tileR,
    const int* __restrict__ off, const int* __restrict__ ntp)
{
    __shared__ bf16 As[BM * BK];
    __shared__ bf16 Bs[BN * BK];
    DECODE_TILE(2, BN)
    f32x4 acc[4][4] = {};
    const bf16* Ab = Ain + (size_t)(base + row0) * HD;
    const bf16* Bb = Bt  + ((size_t)e * OD + n0) * HD;
    GEMM_KLOOP(HD)
    for (int i = 0; i < 4; i++) {
        int rb = wm * 64 + i * 16 + qd * 4;
        for (int r = 0; r < 4; r++) {
            int m = rb + r;
            if (m >= valid) continue;
            int tok = perm[base + row0 + m];
            size_t orow = (size_t)tok * OD;
            for (int j = 0; j < 4; j++) {
                int n = n0 + wn * 64 + j * 16 + lr;
                out[orow + n] = acc[i][j][r] + bias[e * OD + n];
            }
        }
    }
}

// ---------------- launch ----------------
extern "C" void kernel_launch(void* const* d_in, const int* in_sizes, int n_in,
                              void* d_out, int out_size, void* d_ws, size_t ws_size,
                              hipStream_t stream) {
    const float* x   = (const float*)d_in[0];
    const int*   sel = (const int*)d_in[1];
    const float* Wg  = (const float*)d_in[2];
    const float* bg  = (const float*)d_in[3];
    const float* Wu  = (const float*)d_in[4];
    const float* bu  = (const float*)d_in[5];
    const float* W1  = (const float*)d_in[6];
    const float* b1  = (const float*)d_in[7];
    const float* W2  = (const float*)d_in[8];
    const float* b2  = (const float*)d_in[9];
    float* out = (float*)d_out;

    char* ws = (char*)d_ws;
    int* cnt    = (int*)(ws + O_CNT);
    int* cur    = (int*)(ws + O_CUR);
    int* off    = (int*)(ws + O_OFF);
    int* nt     = (int*)(ws + O_NT);
    int* done   = (int*)(ws + O_DONE);
    int* tileE  = (int*)(ws + O_TE);
    int* tileR  = (int*)(ws + O_TR);
    int* perm   = (int*)(ws + O_PERM);
    bf16* Xp    = (bf16*)(ws + O_XP);
    bf16* Wgt   = (bf16*)(ws + O_WG);
    bf16* Wut   = (bf16*)(ws + O_WU);
    bf16* W1t   = (bf16*)(ws + O_W1);
    bf16* W2t   = (bf16*)(ws + O_W2);
    bf16* Hbuf  = (bf16*)(ws + O_H);
    bf16* H2    = (bf16*)(ws + O_H2);

    hipMemsetAsync(ws, 0, 256, stream);   // zeroes cnt/cur/off/nt/done

    k_histplan<<<NTOK / 256, 256, 0, stream>>>(sel, cnt, done, off, tileE, tileR, nt);
    k_scatgath<<<NTOK / 128, 256, 0, stream>>>(sel, off, cur, perm, x, Xp);

    k_transpose_all<<<NEXP * TPE, 256, 0, stream>>>(Wg, Wgt, Wu, Wut, W1, W1t, W2, W2t);

    k_swiglu<<<RT8 * 16 * 8, 256, 0, stream>>>(Xp, Wgt, Wut, bg, bu, Hbuf,
                                               tileE, tileR, off, nt);
    k_gemm2 <<<RT8 * 4 * 8, 256, 0, stream>>>(Hbuf, W1t, b1, H2, 0,
                                              tileE, tileR, off, nt);
    k_gemm2 <<<RT8 * 4 * 8, 256, 0, stream>>>(Hbuf, W1t, b1, H2, 4,
                                              tileE, tileR, off, nt);
    k_gemm3 <<<RT8 * 2 * 8, 256, 0, stream>>>(H2, W2t, b2, out, perm,
                                              tileE, tileR, off, nt);
}

// Round 8
// 322.951 us; speedup vs baseline: 1.1617x; 1.1617x over previous
//
#include <hip/hip_runtime.h>
#include <hip/hip_bf16.h>
#include <cstdint>
#include <cstddef>

// Problem constants
#define NTOK 32768   // P*N*K token-copies
#define FD   256     // input feature dim
#define HD   1024    // hidden dim
#define OD   256     // output dim
#define NEXP 8

// GEMM tiling
#define BM 128
#define BN 128
#define BK 64
#define RT8 34       // ceil(max 128-row tiles / 8)

typedef __bf16 bf16;
typedef __bf16 bf16x8 __attribute__((ext_vector_type(8)));
typedef __bf16 bf16x4 __attribute__((ext_vector_type(4)));
typedef float  f32x4  __attribute__((ext_vector_type(4)));

// async global->LDS, 16 B per lane. LDS dst MUST be wave-uniform base + lane*16.
__device__ __forceinline__ void cp16(const void* g, void* l) {
    __builtin_amdgcn_global_load_lds(
        (const __attribute__((address_space(1))) void*)g,
        (__attribute__((address_space(3))) void*)l, 16, 0, 0);
}

// ---- workspace layout (bytes) ----
static const size_t O_CNT  = 0;          // int[8]
static const size_t O_CUR  = 64;         // int[8]
static const size_t O_OFF  = 128;        // int[9]
static const size_t O_NT   = 192;        // int[1]
static const size_t O_DONE = 240;        // int[1]  (hist last-block ticket)
static const size_t O_TE   = 1024;       // int[<=264 used]
static const size_t O_TR   = 3072;       // int[<=264 used]
static const size_t O_PERM = 5120;       // int[NTOK]
static const size_t O_XP   = 136192;     // bf16 [NTOK][FD]    (16 MB)
static const size_t O_WG   = 16913408;   // bf16 [E][HD][FD]   (4 MB)
static const size_t O_WU   = 21107712;   // bf16 [E][HD][FD]   (4 MB)
static const size_t O_W1   = 25302016;   // bf16 [E][HD][HD]   (16 MB)
static const size_t O_W2   = 42079232;   // bf16 [E][OD][HD]   (4 MB)
static const size_t O_H    = 46273536;   // bf16 [NTOK][HD]    (64 MB) Hbuf
static const size_t O_H2   = 113382400;  // bf16 [NTOK][HD]    (64 MB) H2

// ---------------- routing ----------------
// hist + plan fused: last block (device-scope ticket) runs the serial plan.
__global__ void k_histplan(const int* __restrict__ sel, int* __restrict__ cnt,
                           int* __restrict__ done, int* __restrict__ off,
                           int* __restrict__ tileE, int* __restrict__ tileR,
                           int* __restrict__ nt) {
    __shared__ int lcnt[NEXP];
    int tid = threadIdx.x;
    if (tid < NEXP) lcnt[tid] = 0;
    __syncthreads();
    int t = blockIdx.x * 256 + tid;   // NTOK % 256 == 0
    atomicAdd(&lcnt[sel[t]], 1);
    __syncthreads();
    if (tid < NEXP) atomicAdd(&cnt[tid], lcnt[tid]);
    __syncthreads();                  // block's cnt atomics issued before ticket
    if (tid == 0) {
        __threadfence();              // order cnt RMWs before ticket RMW
        int ret = atomicAdd(done, 1);
        if (ret == (int)gridDim.x - 1) {
            int c[NEXP];
            int o = 0;
            for (int e = 0; e < NEXP; e++) {
                c[e] = atomicAdd(&cnt[e], 0);
                off[e] = o; o += c[e];
            }
            off[NEXP] = o;
            int n = 0;
            for (int e = 0; e < NEXP; e++) {
                int nte = (c[e] + BM - 1) / BM;
                for (int r = 0; r < nte; r++) { tileE[n] = e; tileR[n] = r; n++; }
            }
            *nt = n;
        }
    }
}

// scatter + gather fused: block computes perm for its 128 tokens, then its
// 4 waves copy the rows x[tok] (fp32) -> Xp[pos] (bf16) directly.
__global__ void k_scatgath(const int* __restrict__ sel, const int* __restrict__ off,
                           int* __restrict__ cur, int* __restrict__ perm,
                           const float* __restrict__ x, bf16* __restrict__ Xp) {
    __shared__ int lcnt[NEXP];
    __shared__ int lbase[NEXP];
    __shared__ int lpos[128];
    __shared__ int ltok[128];
    int tid = threadIdx.x;
    if (tid < NEXP) lcnt[tid] = 0;
    __syncthreads();
    int e = 0, rank = 0, t = 0;
    if (tid < 128) {
        t = blockIdx.x * 128 + tid;   // NTOK % 128 == 0, grid = NTOK/128
        e = sel[t];
        rank = atomicAdd(&lcnt[e], 1);
    }
    __syncthreads();
    if (tid < NEXP)
        lbase[tid] = atomicAdd(&cur[tid], lcnt[tid]);
    __syncthreads();
    if (tid < 128) {
        int pos = off[e] + lbase[e] + rank;
        perm[pos] = t;
        lpos[tid] = pos;
        ltok[tid] = t;
    }
    __syncthreads();
    int lane = tid & 63, wv = tid >> 6;
    for (int r = wv; r < 128; r += 4) {
        int tok = ltok[r], pos = lpos[r];
        float4 v = ((const float4*)x)[(size_t)tok * 64 + lane];
        bf16x4 o;
        o.x = (bf16)v.x; o.y = (bf16)v.y; o.z = (bf16)v.z; o.w = (bf16)v.w;
        *(bf16x4*)&Xp[(size_t)pos * FD + lane * 4] = o;
    }
}

// All 4 weight transposes in ONE launch. W [E][K][N] fp32 -> Wt [E][N][K] bf16.
#define TPE 448
__global__ void k_transpose_all(const float* __restrict__ Wg, bf16* __restrict__ Wgt,
                                const float* __restrict__ Wu, bf16* __restrict__ Wut,
                                const float* __restrict__ W1, bf16* __restrict__ W1t,
                                const float* __restrict__ W2, bf16* __restrict__ W2t) {
    __shared__ float tile[64][65];
    int b  = blockIdx.x;
    int e  = b / TPE;
    int tt = b % TPE;
    const float* Ws; bf16* Wd; int K, N;
    if (tt < 64)       { Ws = Wg; Wd = Wgt; K = FD; N = HD; }
    else if (tt < 128) { Ws = Wu; Wd = Wut; K = FD; N = HD; tt -= 64; }
    else if (tt < 384) { Ws = W1; Wd = W1t; K = HD; N = HD; tt -= 128; }
    else               { Ws = W2; Wd = W2t; K = HD; N = OD; tt -= 384; }
    int nk = K / 64;
    int k0 = (tt % nk) * 64, n0 = (tt / nk) * 64;
    Ws += (size_t)e * K * N;
    Wd += (size_t)e * K * N;
    int t = threadIdx.x;
    for (int q = 0; q < 4; q++) {
        int lin = t + q * 256;
        int r = lin >> 4, c4 = (lin & 15) * 4;
        float4 v = *(const float4*)&Ws[(size_t)(k0 + r) * N + n0 + c4];
        tile[r][c4] = v.x; tile[r][c4+1] = v.y; tile[r][c4+2] = v.z; tile[r][c4+3] = v.w;
    }
    __syncthreads();
    for (int q = 0; q < 2; q++) {   // 64 n * 8 chunks = 512 items
        int lin = t + q * 256;
        int n = lin >> 3, k8 = (lin & 7) * 8;
        bf16x8 o;
        for (int i = 0; i < 8; i++) o[i] = (bf16)tile[k8 + i][n];
        *(bf16x8*)&Wd[(size_t)(n0 + n) * K + k0 + k8] = o;
    }
}

// ---------------- GEMM kernels ----------------
// MFMA 16x16x32 bf16 (HW-verified layouts). BK=64: 2 k-steps per barrier.
// LDS: unpadded [rows][64], XOR chunk swizzle over 8 chunks/row.
// XCD swizzle: 1D grid, xcd=L&7 -> all n-tiles of a row-tile on one XCD.
// NOTE (R7 lesson): do NOT split a GEMM over N into separate dispatches --
// the second dispatch re-reads the whole A panel from HBM after L2 eviction
// (~+30us for gemm2).

#define DECODE_TILE(NTY, BNE)                                                  \
    int L = blockIdx.x;                                                        \
    int xcd = L & 7; int tq = L >> 3;                                          \
    int ny  = tq % (NTY); int Rhi = tq / (NTY);                                \
    int R   = Rhi * 8 + xcd;                                                   \
    if (R >= *ntp) return;                                                     \
    int e    = tileE[R];                                                       \
    int row0 = tileR[R] * BM;                                                  \
    int base = off[e];                                                         \
    int valid = off[e + 1] - base - row0; if (valid > BM) valid = BM;          \
    int n0 = ny * (BNE);                                                       \
    int tid = threadIdx.x;                                                     \
    int lane = tid & 63, wv = tid >> 6;                                        \
    int wm = wv & 1, wn = wv >> 1;                                             \
    int lr = lane & 15, qd = lane >> 4;

#define GEMM_KLOOP(KDIM)                                                       \
    for (int k0 = 0; k0 < (KDIM); k0 += BK) {                                  \
        for (int s = 0; s < 4; s++) {                                          \
            int ci = tid + s * 256;                                            \
            int row = ci >> 3;                                                 \
            int jg  = (ci & 7) ^ (row & 7);                                    \
            int mc  = row < valid ? row : valid - 1;                           \
            cp16(Ab + (size_t)mc  * (KDIM) + k0 + jg * 8, &As[ci * 8]);        \
            cp16(Bb + (size_t)row * (KDIM) + k0 + jg * 8, &Bs[ci * 8]);        \
        }                                                                      \
        __syncthreads();                                                       \
        for (int ks = 0; ks < 2; ks++) {                                       \
            bf16x8 af[4], bfr[4];                                              \
            for (int i = 0; i < 4; i++) {                                      \
                int row = wm * 64 + i * 16 + lr;                               \
                int sl  = (ks * 4 + qd) ^ (row & 7);                           \
                af[i] = *(const bf16x8*)&As[row * BK + sl * 8];                \
            }                                                                  \
            for (int j = 0; j < 4; j++) {                                      \
                int row = wn * 64 + j * 16 + lr;                               \
                int sl  = (ks * 4 + qd) ^ (row & 7);                           \
                bfr[j] = *(const bf16x8*)&Bs[row * BK + sl * 8];               \
            }                                                                  \
            for (int i = 0; i < 4; i++)                                        \
                for (int j = 0; j < 4; j++)                                    \
                    acc[i][j] = __builtin_amdgcn_mfma_f32_16x16x32_bf16(       \
                        af[i], bfr[j], acc[i][j], 0, 0, 0);                    \
        }                                                                      \
        __syncthreads();                                                       \
    }

// Fused SwiGLU: Hbuf = silu(Xp@Wg+bg) * (Xp@Wu+bu). BM=128 x BN=64, K=FD=256.
// R7 PMC: VALU-bound (45.6% VALUBusy vs 22.5% MfmaUtil). Epilogue fix: the
// IEEE divide in silu compiled to the full v_div_scale/fmas/fixup sequence
// (~9 VALU/elem x 32 elems); replaced with v_rcp_f32 (1 ulp, invisible under
// bf16 rounding). Bias values hoisted (2 distinct per thread, not 32).
__global__ __launch_bounds__(256, 4) void k_swiglu(
    const bf16* __restrict__ Xp, const bf16* __restrict__ Wgt, const bf16* __restrict__ Wut,
    const float* __restrict__ bg, const float* __restrict__ bu, bf16* __restrict__ Hbuf,
    const int* __restrict__ tileE, const int* __restrict__ tileR,
    const int* __restrict__ off, const int* __restrict__ ntp)
{
    __shared__ bf16 As [BM * BK];        // 16 KB
    __shared__ bf16 Bgs[64 * BK];        // 8 KB
    __shared__ bf16 Bus[64 * BK];        // 8 KB
    DECODE_TILE(16, 64)

    f32x4 accg[4][2] = {};
    f32x4 accu[4][2] = {};
    const bf16* Ab  = Xp  + (size_t)(base + row0) * FD;
    const bf16* Bgb = Wgt + ((size_t)e * HD + n0) * FD;
    const bf16* Bub = Wut + ((size_t)e * HD + n0) * FD;

    for (int k0 = 0; k0 < FD; k0 += BK) {
        for (int s = 0; s < 4; s++) {                  // A: 1024 chunks
            int ci = tid + s * 256;
            int row = ci >> 3;
            int jg  = (ci & 7) ^ (row & 7);
            int mc  = row < valid ? row : valid - 1;
            cp16(Ab + (size_t)mc * FD + k0 + jg * 8, &As[ci * 8]);
        }
        for (int s = 0; s < 2; s++) {                  // Bg,Bu: 512 chunks each
            int ci = tid + s * 256;
            int row = ci >> 3;
            int jg  = (ci & 7) ^ (row & 7);
            cp16(Bgb + (size_t)row * FD + k0 + jg * 8, &Bgs[ci * 8]);
            cp16(Bub + (size_t)row * FD + k0 + jg * 8, &Bus[ci * 8]);
        }
        __syncthreads();
        for (int ks = 0; ks < 2; ks++) {
            bf16x8 af[4], bgf[2], buf[2];
            for (int i = 0; i < 4; i++) {
                int row = wm * 64 + i * 16 + lr;
                int sl  = (ks * 4 + qd) ^ (row & 7);
                af[i] = *(const bf16x8*)&As[row * BK + sl * 8];
            }
            for (int j = 0; j < 2; j++) {
                int row = wn * 32 + j * 16 + lr;
                int sl  = (ks * 4 + qd) ^ (row & 7);
                bgf[j] = *(const bf16x8*)&Bgs[row * BK + sl * 8];
                buf[j] = *(const bf16x8*)&Bus[row * BK + sl * 8];
            }
            for (int i = 0; i < 4; i++)
                for (int j = 0; j < 2; j++) {
                    accg[i][j] = __builtin_amdgcn_mfma_f32_16x16x32_bf16(af[i], bgf[j], accg[i][j], 0, 0, 0);
                    accu[i][j] = __builtin_amdgcn_mfma_f32_16x16x32_bf16(af[i], buf[j], accu[i][j], 0, 0, 0);
                }
        }
        __syncthreads();
    }
    // epilogue: bias hoist + rcp-based silu
    float bgv[2], buv[2];
    int ncol[2];
    #pragma unroll
    for (int j = 0; j < 2; j++) {
        ncol[j] = n0 + wn * 32 + j * 16 + lr;
        bgv[j] = bg[e * HD + ncol[j]];
        buv[j] = bu[e * HD + ncol[j]];
    }
    for (int i = 0; i < 4; i++) {
        int rb = wm * 64 + i * 16 + qd * 4;
        for (int r = 0; r < 4; r++) {
            int m = rb + r;
            if (m >= valid) continue;
            size_t orow = (size_t)(base + row0 + m) * HD;
            #pragma unroll
            for (int j = 0; j < 2; j++) {
                float g = accg[i][j][r] + bgv[j];
                float u = accu[i][j][r] + buv[j];
                float s = __builtin_amdgcn_rcpf(1.f + __expf(-g));  // sigmoid
                Hbuf[orow + ncol[j]] = (bf16)(g * u * s);
            }
        }
    }
}

// gemm2: H2 = relu(Hbuf@W1 + b1). K=HD, NTY=8.  (single dispatch -- R7 lesson)
__global__ __launch_bounds__(256, 4) void k_gemm2(
    const bf16* __restrict__ Ain, const bf16* __restrict__ Bt, const float* __restrict__ bias,
    bf16* __restrict__ Out,
    const int* __restrict__ tileE, const int* __restrict__ tileR,
    const int* __restrict__ off, const int* __restrict__ ntp)
{
    __shared__ bf16 As[BM * BK];   // 16 KB
    __shared__ bf16 Bs[BN * BK];   // 16 KB
    DECODE_TILE(8, BN)
    f32x4 acc[4][4] = {};
    const bf16* Ab = Ain + (size_t)(base + row0) * HD;
    const bf16* Bb = Bt  + ((size_t)e * HD + n0) * HD;
    GEMM_KLOOP(HD)
    for (int i = 0; i < 4; i++) {
        int rb = wm * 64 + i * 16 + qd * 4;
        for (int r = 0; r < 4; r++) {
            int m = rb + r;
            if (m >= valid) continue;
            size_t orow = (size_t)(base + row0 + m) * HD;
            for (int j = 0; j < 4; j++) {
                int n = n0 + wn * 64 + j * 16 + lr;
                float v = acc[i][j][r] + bias[e * HD + n];
                Out[orow + n] = (bf16)(v > 0.f ? v : 0.f);
            }
        }
    }
}

// gemm3: out[perm] = H2@W2 + b2 (fp32 scatter). K=HD, NTY=2.
__global__ __launch_bounds__(256, 4) void k_gemm3(
    const bf16* __restrict__ Ain, const bf16* __restrict__ Bt, const float* __restrict__ bias,
    float* __restrict__ out, const int* __restrict__ perm,
    const int* __restrict__ tileE, const int* __restrict__ tileR,
    const int* __restrict__ off, const int* __restrict__ ntp)
{
    __shared__ bf16 As[BM * BK];
    __shared__ bf16 Bs[BN * BK];
    DECODE_TILE(2, BN)
    f32x4 acc[4][4] = {};
    const bf16* Ab = Ain + (size_t)(base + row0) * HD;
    const bf16* Bb = Bt  + ((size_t)e * OD + n0) * HD;
    GEMM_KLOOP(HD)
    for (int i = 0; i < 4; i++) {
        int rb = wm * 64 + i * 16 + qd * 4;
        for (int r = 0; r < 4; r++) {
            int m = rb + r;
            if (m >= valid) continue;
            int tok = perm[base + row0 + m];
            size_t orow = (size_t)tok * OD;
            for (int j = 0; j < 4; j++) {
                int n = n0 + wn * 64 + j * 16 + lr;
                out[orow + n] = acc[i][j][r] + bias[e * OD + n];
            }
        }
    }
}

// ---------------- launch ----------------
extern "C" void kernel_launch(void* const* d_in, const int* in_sizes, int n_in,
                              void* d_out, int out_size, void* d_ws, size_t ws_size,
                              hipStream_t stream) {
    const float* x   = (const float*)d_in[0];
    const int*   sel = (const int*)d_in[1];
    const float* Wg  = (const float*)d_in[2];
    const float* bg  = (const float*)d_in[3];
    const float* Wu  = (const float*)d_in[4];
    const float* bu  = (const float*)d_in[5];
    const float* W1  = (const float*)d_in[6];
    const float* b1  = (const float*)d_in[7];
    const float* W2  = (const float*)d_in[8];
    const float* b2  = (const float*)d_in[9];
    float* out = (float*)d_out;

    char* ws = (char*)d_ws;
    int* cnt    = (int*)(ws + O_CNT);
    int* cur    = (int*)(ws + O_CUR);
    int* off    = (int*)(ws + O_OFF);
    int* nt     = (int*)(ws + O_NT);
    int* done   = (int*)(ws + O_DONE);
    int* tileE  = (int*)(ws + O_TE);
    int* tileR  = (int*)(ws + O_TR);
    int* perm   = (int*)(ws + O_PERM);
    bf16* Xp    = (bf16*)(ws + O_XP);
    bf16* Wgt   = (bf16*)(ws + O_WG);
    bf16* Wut   = (bf16*)(ws + O_WU);
    bf16* W1t   = (bf16*)(ws + O_W1);
    bf16* W2t   = (bf16*)(ws + O_W2);
    bf16* Hbuf  = (bf16*)(ws + O_H);
    bf16* H2    = (bf16*)(ws + O_H2);

    hipMemsetAsync(ws, 0, 256, stream);   // zeroes cnt/cur/off/nt/done

    k_histplan<<<NTOK / 256, 256, 0, stream>>>(sel, cnt, done, off, tileE, tileR, nt);
    k_scatgath<<<NTOK / 128, 256, 0, stream>>>(sel, off, cur, perm, x, Xp);

    k_transpose_all<<<NEXP * TPE, 256, 0, stream>>>(Wg, Wgt, Wu, Wut, W1, W1t, W2, W2t);

    k_swiglu<<<RT8 * 16 * 8, 256, 0, stream>>>(Xp, Wgt, Wut, bg, bu, Hbuf,
                                               tileE, tileR, off, nt);
    k_gemm2 <<<RT8 * 8 * 8, 256, 0, stream>>>(Hbuf, W1t, b1, H2,
                                              tileE, tileR, off, nt);
    k_gemm3 <<<RT8 * 2 * 8, 256, 0, stream>>>(H2, W2t, b2, out, perm,
                                              tileE, tileR, off, nt);
}

// Round 9
// 314.970 us; speedup vs baseline: 1.1912x; 1.0253x over previous
//
#include <hip/hip_runtime.h>
#include <hip/hip_bf16.h>
#include <cstdint>
#include <cstddef>

// Problem constants
#define NTOK 32768   // P*N*K token-copies
#define FD   256     // input feature dim
#define HD   1024    // hidden dim
#define OD   256     // output dim
#define NEXP 8

// GEMM tiling
#define BM 128
#define BN 128
#define BK 64
#define RT8 34       // ceil(max 128-row tiles / 8)

typedef __bf16 bf16;
typedef __bf16 bf16x8 __attribute__((ext_vector_type(8)));
typedef __bf16 bf16x4 __attribute__((ext_vector_type(4)));
typedef float  f32x4  __attribute__((ext_vector_type(4)));

// async global->LDS, 16 B per lane. LDS dst MUST be wave-uniform base + lane*16.
__device__ __forceinline__ void cp16(const void* g, void* l) {
    __builtin_amdgcn_global_load_lds(
        (const __attribute__((address_space(1))) void*)g,
        (__attribute__((address_space(3))) void*)l, 16, 0, 0);
}

// ---- workspace layout (bytes) ----
static const size_t O_CNT  = 0;          // int[8]
static const size_t O_CUR  = 64;         // int[8]
static const size_t O_OFF  = 128;        // int[9]
static const size_t O_NT   = 192;        // int[1]
static const size_t O_DONE = 240;        // int[1]  (hist last-block ticket)
static const size_t O_TE   = 1024;       // int[<=264 used]
static const size_t O_TR   = 3072;       // int[<=264 used]
static const size_t O_PERM = 5120;       // int[NTOK]
static const size_t O_XP   = 136192;     // bf16 [NTOK][FD]    (16 MB)
static const size_t O_WG   = 16913408;   // bf16 [E][HD][FD]   (4 MB)
static const size_t O_WU   = 21107712;   // bf16 [E][HD][FD]   (4 MB)
static const size_t O_W1   = 25302016;   // bf16 [E][HD][HD]   (16 MB)
static const size_t O_W2   = 42079232;   // bf16 [E][OD][HD]   (4 MB)
static const size_t O_H    = 46273536;   // bf16 [NTOK][HD]    (64 MB) Hbuf
static const size_t O_H2   = 113382400;  // bf16 [NTOK][HD]    (64 MB) H2

// ---------------- routing ----------------
// hist + plan fused: last block (device-scope ticket) runs the serial plan.
__global__ void k_histplan(const int* __restrict__ sel, int* __restrict__ cnt,
                           int* __restrict__ done, int* __restrict__ off,
                           int* __restrict__ tileE, int* __restrict__ tileR,
                           int* __restrict__ nt) {
    __shared__ int lcnt[NEXP];
    int tid = threadIdx.x;
    if (tid < NEXP) lcnt[tid] = 0;
    __syncthreads();
    int t = blockIdx.x * 256 + tid;   // NTOK % 256 == 0
    atomicAdd(&lcnt[sel[t]], 1);
    __syncthreads();
    if (tid < NEXP) atomicAdd(&cnt[tid], lcnt[tid]);
    __syncthreads();                  // block's cnt atomics issued before ticket
    if (tid == 0) {
        __threadfence();              // order cnt RMWs before ticket RMW
        int ret = atomicAdd(done, 1);
        if (ret == (int)gridDim.x - 1) {
            int c[NEXP];
            int o = 0;
            for (int e = 0; e < NEXP; e++) {
                c[e] = atomicAdd(&cnt[e], 0);
                off[e] = o; o += c[e];
            }
            off[NEXP] = o;
            int n = 0;
            for (int e = 0; e < NEXP; e++) {
                int nte = (c[e] + BM - 1) / BM;
                for (int r = 0; r < nte; r++) { tileE[n] = e; tileR[n] = r; n++; }
            }
            *nt = n;
        }
    }
}

// prep: scatter+gather (blocks 0..NTOK/128-1) and the 4 weight transposes
// (remaining blocks) in ONE dispatch. The two halves are data-independent;
// fusing removes a stream boundary and overlaps the scatter's atomic/copy
// latency under the transpose's HBM streaming.
#define SGBLK (NTOK / 128)   // 256 scatter blocks
#define TPE 448              // transpose tiles per expert

__device__ __forceinline__ void do_scatgath(
    int b, const int* __restrict__ sel, const int* __restrict__ off,
    int* __restrict__ cur, int* __restrict__ perm,
    const float* __restrict__ x, bf16* __restrict__ Xp) {
    __shared__ int lcnt[NEXP];
    __shared__ int lbase[NEXP];
    __shared__ int lpos[128];
    __shared__ int ltok[128];
    int tid = threadIdx.x;
    if (tid < NEXP) lcnt[tid] = 0;
    __syncthreads();
    int e = 0, rank = 0, t = 0;
    if (tid < 128) {
        t = b * 128 + tid;
        e = sel[t];
        rank = atomicAdd(&lcnt[e], 1);
    }
    __syncthreads();
    if (tid < NEXP)
        lbase[tid] = atomicAdd(&cur[tid], lcnt[tid]);
    __syncthreads();
    if (tid < 128) {
        int pos = off[e] + lbase[e] + rank;
        perm[pos] = t;
        lpos[tid] = pos;
        ltok[tid] = t;
    }
    __syncthreads();
    int lane = tid & 63, wv = tid >> 6;
    for (int r = wv; r < 128; r += 4) {
        int tok = ltok[r], pos = lpos[r];
        float4 v = ((const float4*)x)[(size_t)tok * 64 + lane];
        bf16x4 o;
        o.x = (bf16)v.x; o.y = (bf16)v.y; o.z = (bf16)v.z; o.w = (bf16)v.w;
        *(bf16x4*)&Xp[(size_t)pos * FD + lane * 4] = o;
    }
}

__device__ __forceinline__ void do_transpose(
    int b, const float* __restrict__ Wg, bf16* __restrict__ Wgt,
    const float* __restrict__ Wu, bf16* __restrict__ Wut,
    const float* __restrict__ W1, bf16* __restrict__ W1t,
    const float* __restrict__ W2, bf16* __restrict__ W2t) {
    __shared__ float tile[64][65];
    int e  = b / TPE;
    int tt = b % TPE;
    const float* Ws; bf16* Wd; int K, N;
    if (tt < 64)       { Ws = Wg; Wd = Wgt; K = FD; N = HD; }
    else if (tt < 128) { Ws = Wu; Wd = Wut; K = FD; N = HD; tt -= 64; }
    else if (tt < 384) { Ws = W1; Wd = W1t; K = HD; N = HD; tt -= 128; }
    else               { Ws = W2; Wd = W2t; K = HD; N = OD; tt -= 384; }
    int nk = K / 64;
    int k0 = (tt % nk) * 64, n0 = (tt / nk) * 64;
    Ws += (size_t)e * K * N;
    Wd += (size_t)e * K * N;
    int t = threadIdx.x;
    for (int q = 0; q < 4; q++) {
        int lin = t + q * 256;
        int r = lin >> 4, c4 = (lin & 15) * 4;
        float4 v = *(const float4*)&Ws[(size_t)(k0 + r) * N + n0 + c4];
        tile[r][c4] = v.x; tile[r][c4+1] = v.y; tile[r][c4+2] = v.z; tile[r][c4+3] = v.w;
    }
    __syncthreads();
    for (int q = 0; q < 2; q++) {   // 64 n * 8 chunks = 512 items
        int lin = t + q * 256;
        int n = lin >> 3, k8 = (lin & 7) * 8;
        bf16x8 o;
        for (int i = 0; i < 8; i++) o[i] = (bf16)tile[k8 + i][n];
        *(bf16x8*)&Wd[(size_t)(n0 + n) * K + k0 + k8] = o;
    }
}

__global__ void k_prep(const int* __restrict__ sel, const int* __restrict__ off,
                       int* __restrict__ cur, int* __restrict__ perm,
                       const float* __restrict__ x, bf16* __restrict__ Xp,
                       const float* __restrict__ Wg, bf16* __restrict__ Wgt,
                       const float* __restrict__ Wu, bf16* __restrict__ Wut,
                       const float* __restrict__ W1, bf16* __restrict__ W1t,
                       const float* __restrict__ W2, bf16* __restrict__ W2t) {
    int b = blockIdx.x;
    if (b < SGBLK) do_scatgath(b, sel, off, cur, perm, x, Xp);
    else           do_transpose(b - SGBLK, Wg, Wgt, Wu, Wut, W1, W1t, W2, W2t);
}

// ---------------- GEMM kernels ----------------
// MFMA 16x16x32 bf16 (HW-verified layouts). BK=64: 2 k-steps per barrier.
// LDS: unpadded [rows][64], XOR chunk swizzle over 8 chunks/row.
// XCD swizzle: 1D grid, xcd=L&7 -> all n-tiles of a row-tile on one XCD.
// NOTE (R7 lesson): do NOT split a GEMM over N into separate dispatches --
// the second dispatch re-reads the whole A panel from HBM after L2 eviction.

#define DECODE_TILE(NTY, BNE)                                                  \
    int L = blockIdx.x;                                                        \
    int xcd = L & 7; int tq = L >> 3;                                          \
    int ny  = tq % (NTY); int Rhi = tq / (NTY);                                \
    int R   = Rhi * 8 + xcd;                                                   \
    if (R >= *ntp) return;                                                     \
    int e    = tileE[R];                                                       \
    int row0 = tileR[R] * BM;                                                  \
    int base = off[e];                                                         \
    int valid = off[e + 1] - base - row0; if (valid > BM) valid = BM;          \
    int n0 = ny * (BNE);                                                       \
    int tid = threadIdx.x;                                                     \
    int lane = tid & 63, wv = tid >> 6;                                        \
    int wm = wv & 1, wn = wv >> 1;                                             \
    int lr = lane & 15, qd = lane >> 4;

#define GEMM_KLOOP(KDIM)                                                       \
    for (int k0 = 0; k0 < (KDIM); k0 += BK) {                                  \
        for (int s = 0; s < 4; s++) {                                          \
            int ci = tid + s * 256;                                            \
            int row = ci >> 3;                                                 \
            int jg  = (ci & 7) ^ (row & 7);                                    \
            int mc  = row < valid ? row : valid - 1;                           \
            cp16(Ab + (size_t)mc  * (KDIM) + k0 + jg * 8, &As[ci * 8]);        \
            cp16(Bb + (size_t)row * (KDIM) + k0 + jg * 8, &Bs[ci * 8]);        \
        }                                                                      \
        __syncthreads();                                                       \
        for (int ks = 0; ks < 2; ks++) {                                       \
            bf16x8 af[4], bfr[4];                                              \
            for (int i = 0; i < 4; i++) {                                      \
                int row = wm * 64 + i * 16 + lr;                               \
                int sl  = (ks * 4 + qd) ^ (row & 7);                           \
                af[i] = *(const bf16x8*)&As[row * BK + sl * 8];                \
            }                                                                  \
            for (int j = 0; j < 4; j++) {                                      \
                int row = wn * 64 + j * 16 + lr;                               \
                int sl  = (ks * 4 + qd) ^ (row & 7);                           \
                bfr[j] = *(const bf16x8*)&Bs[row * BK + sl * 8];               \
            }                                                                  \
            for (int i = 0; i < 4; i++)                                        \
                for (int j = 0; j < 4; j++)                                    \
                    acc[i][j] = __builtin_amdgcn_mfma_f32_16x16x32_bf16(       \
                        af[i], bfr[j], acc[i][j], 0, 0, 0);                    \
        }                                                                      \
        __syncthreads();                                                       \
    }

// Fused SwiGLU: Hbuf = silu(Xp@Wg+bg) * (Xp@Wu+bu). BM=128 x BN=64, K=FD=256.
// R8 WIN: rcp-based silu + bias hoist fixed the VALU-bound epilogue
// (was 45.6% VALUBusy / 63us; IEEE div = ~9 VALU/elem x 32 elems).
__global__ __launch_bounds__(256, 4) void k_swiglu(
    const bf16* __restrict__ Xp, const bf16* __restrict__ Wgt, const bf16* __restrict__ Wut,
    const float* __restrict__ bg, const float* __restrict__ bu, bf16* __restrict__ Hbuf,
    const int* __restrict__ tileE, const int* __restrict__ tileR,
    const int* __restrict__ off, const int* __restrict__ ntp)
{
    __shared__ bf16 As [BM * BK];        // 16 KB
    __shared__ bf16 Bgs[64 * BK];        // 8 KB
    __shared__ bf16 Bus[64 * BK];        // 8 KB
    DECODE_TILE(16, 64)

    f32x4 accg[4][2] = {};
    f32x4 accu[4][2] = {};
    const bf16* Ab  = Xp  + (size_t)(base + row0) * FD;
    const bf16* Bgb = Wgt + ((size_t)e * HD + n0) * FD;
    const bf16* Bub = Wut + ((size_t)e * HD + n0) * FD;

    for (int k0 = 0; k0 < FD; k0 += BK) {
        for (int s = 0; s < 4; s++) {                  // A: 1024 chunks
            int ci = tid + s * 256;
            int row = ci >> 3;
            int jg  = (ci & 7) ^ (row & 7);
            int mc  = row < valid ? row : valid - 1;
            cp16(Ab + (size_t)mc * FD + k0 + jg * 8, &As[ci * 8]);
        }
        for (int s = 0; s < 2; s++) {                  // Bg,Bu: 512 chunks each
            int ci = tid + s * 256;
            int row = ci >> 3;
            int jg  = (ci & 7) ^ (row & 7);
            cp16(Bgb + (size_t)row * FD + k0 + jg * 8, &Bgs[ci * 8]);
            cp16(Bub + (size_t)row * FD + k0 + jg * 8, &Bus[ci * 8]);
        }
        __syncthreads();
        for (int ks = 0; ks < 2; ks++) {
            bf16x8 af[4], bgf[2], buf[2];
            for (int i = 0; i < 4; i++) {
                int row = wm * 64 + i * 16 + lr;
                int sl  = (ks * 4 + qd) ^ (row & 7);
                af[i] = *(const bf16x8*)&As[row * BK + sl * 8];
            }
            for (int j = 0; j < 2; j++) {
                int row = wn * 32 + j * 16 + lr;
                int sl  = (ks * 4 + qd) ^ (row & 7);
                bgf[j] = *(const bf16x8*)&Bgs[row * BK + sl * 8];
                buf[j] = *(const bf16x8*)&Bus[row * BK + sl * 8];
            }
            for (int i = 0; i < 4; i++)
                for (int j = 0; j < 2; j++) {
                    accg[i][j] = __builtin_amdgcn_mfma_f32_16x16x32_bf16(af[i], bgf[j], accg[i][j], 0, 0, 0);
                    accu[i][j] = __builtin_amdgcn_mfma_f32_16x16x32_bf16(af[i], buf[j], accu[i][j], 0, 0, 0);
                }
        }
        __syncthreads();
    }
    // epilogue: bias hoist + rcp-based silu
    float bgv[2], buv[2];
    int ncol[2];
    #pragma unroll
    for (int j = 0; j < 2; j++) {
        ncol[j] = n0 + wn * 32 + j * 16 + lr;
        bgv[j] = bg[e * HD + ncol[j]];
        buv[j] = bu[e * HD + ncol[j]];
    }
    for (int i = 0; i < 4; i++) {
        int rb = wm * 64 + i * 16 + qd * 4;
        for (int r = 0; r < 4; r++) {
            int m = rb + r;
            if (m >= valid) continue;
            size_t orow = (size_t)(base + row0 + m) * HD;
            #pragma unroll
            for (int j = 0; j < 2; j++) {
                float g = accg[i][j][r] + bgv[j];
                float u = accu[i][j][r] + buv[j];
                float s = __builtin_amdgcn_rcpf(1.f + __expf(-g));  // sigmoid
                Hbuf[orow + ncol[j]] = (bf16)(g * u * s);
            }
        }
    }
}

// gemm2: H2 = relu(Hbuf@W1 + b1). K=HD, NTY=8. Bias hoisted (4 loads).
__global__ __launch_bounds__(256, 4) void k_gemm2(
    const bf16* __restrict__ Ain, const bf16* __restrict__ Bt, const float* __restrict__ bias,
    bf16* __restrict__ Out,
    const int* __restrict__ tileE, const int* __restrict__ tileR,
    const int* __restrict__ off, const int* __restrict__ ntp)
{
    __shared__ bf16 As[BM * BK];   // 16 KB
    __shared__ bf16 Bs[BN * BK];   // 16 KB
    DECODE_TILE(8, BN)
    f32x4 acc[4][4] = {};
    const bf16* Ab = Ain + (size_t)(base + row0) * HD;
    const bf16* Bb = Bt  + ((size_t)e * HD + n0) * HD;
    GEMM_KLOOP(HD)
    float bj[4];
    int ncol[4];
    #pragma unroll
    for (int j = 0; j < 4; j++) {
        ncol[j] = n0 + wn * 64 + j * 16 + lr;
        bj[j] = bias[e * HD + ncol[j]];
    }
    for (int i = 0; i < 4; i++) {
        int rb = wm * 64 + i * 16 + qd * 4;
        for (int r = 0; r < 4; r++) {
            int m = rb + r;
            if (m >= valid) continue;
            size_t orow = (size_t)(base + row0 + m) * HD;
            #pragma unroll
            for (int j = 0; j < 4; j++) {
                float v = acc[i][j][r] + bj[j];
                Out[orow + ncol[j]] = (bf16)(v > 0.f ? v : 0.f);
            }
        }
    }
}

// gemm3: out[perm] = H2@W2 + b2 (fp32 scatter). K=HD, NTY=2. Bias hoisted.
__global__ __launch_bounds__(256, 4) void k_gemm3(
    const bf16* __restrict__ Ain, const bf16* __restrict__ Bt, const float* __restrict__ bias,
    float* __restrict__ out, const int* __restrict__ perm,
    const int* __restrict__ tileE, const int* __restrict__ tileR,
    const int* __restrict__ off, const int* __restrict__ ntp)
{
    __shared__ bf16 As[BM * BK];
    __shared__ bf16 Bs[BN * BK];
    DECODE_TILE(2, BN)
    f32x4 acc[4][4] = {};
    const bf16* Ab = Ain + (size_t)(base + row0) * HD;
    const bf16* Bb = Bt  + ((size_t)e * OD + n0) * HD;
    GEMM_KLOOP(HD)
    float bj[4];
    int ncol[4];
    #pragma unroll
    for (int j = 0; j < 4; j++) {
        ncol[j] = n0 + wn * 64 + j * 16 + lr;
        bj[j] = bias[e * OD + ncol[j]];
    }
    for (int i = 0; i < 4; i++) {
        int rb = wm * 64 + i * 16 + qd * 4;
        for (int r = 0; r < 4; r++) {
            int m = rb + r;
            if (m >= valid) continue;
            int tok = perm[base + row0 + m];
            size_t orow = (size_t)tok * OD;
            #pragma unroll
            for (int j = 0; j < 4; j++) {
                out[orow + ncol[j]] = acc[i][j][r] + bj[j];
            }
        }
    }
}

// ---------------- launch ----------------
extern "C" void kernel_launch(void* const* d_in, const int* in_sizes, int n_in,
                              void* d_out, int out_size, void* d_ws, size_t ws_size,
                              hipStream_t stream) {
    const float* x   = (const float*)d_in[0];
    const int*   sel = (const int*)d_in[1];
    const float* Wg  = (const float*)d_in[2];
    const float* bg  = (const float*)d_in[3];
    const float* Wu  = (const float*)d_in[4];
    const float* bu  = (const float*)d_in[5];
    const float* W1  = (const float*)d_in[6];
    const float* b1  = (const float*)d_in[7];
    const float* W2  = (const float*)d_in[8];
    const float* b2  = (const float*)d_in[9];
    float* out = (float*)d_out;

    char* ws = (char*)d_ws;
    int* cnt    = (int*)(ws + O_CNT);
    int* cur    = (int*)(ws + O_CUR);
    int* off    = (int*)(ws + O_OFF);
    int* nt     = (int*)(ws + O_NT);
    int* done   = (int*)(ws + O_DONE);
    int* tileE  = (int*)(ws + O_TE);
    int* tileR  = (int*)(ws + O_TR);
    int* perm   = (int*)(ws + O_PERM);
    bf16* Xp    = (bf16*)(ws + O_XP);
    bf16* Wgt   = (bf16*)(ws + O_WG);
    bf16* Wut   = (bf16*)(ws + O_WU);
    bf16* W1t   = (bf16*)(ws + O_W1);
    bf16* W2t   = (bf16*)(ws + O_W2);
    bf16* Hbuf  = (bf16*)(ws + O_H);
    bf16* H2    = (bf16*)(ws + O_H2);

    hipMemsetAsync(ws, 0, 256, stream);   // zeroes cnt/cur/off/nt/done

    k_histplan<<<NTOK / 256, 256, 0, stream>>>(sel, cnt, done, off, tileE, tileR, nt);

    // scatgath (256 blocks) + all weight transposes (3584 blocks), one dispatch
    k_prep<<<SGBLK + NEXP * TPE, 256, 0, stream>>>(sel, off, cur, perm, x, Xp,
                                                   Wg, Wgt, Wu, Wut,
                                                   W1, W1t, W2, W2t);

    k_swiglu<<<RT8 * 16 * 8, 256, 0, stream>>>(Xp, Wgt, Wut, bg, bu, Hbuf,
                                               tileE, tileR, off, nt);
    k_gemm2 <<<RT8 * 8 * 8, 256, 0, stream>>>(Hbuf, W1t, b1, H2,
                                              tileE, tileR, off, nt);
    k_gemm3 <<<RT8 * 2 * 8, 256, 0, stream>>>(H2, W2t, b2, out, perm,
                                              tileE, tileR, off, nt);
}